// Round 7
// baseline (931.191 us; speedup 1.0000x reference)
//
#include <hip/hip_runtime.h>
#include <cstdint>

#define B_ 4096
#define F_ 1024
#define H_ 16384
#define TOPK 64
#define MAXC 192
#define NBINS 2048
#define RG 16    // rows per refine block
#define TW 512   // h-columns per refine tile
#define WLCAP (RG * MAXC)

typedef unsigned short u16;
typedef __attribute__((ext_vector_type(8))) short bf16x8;
typedef __attribute__((ext_vector_type(8))) unsigned short u16x8;
typedef __attribute__((ext_vector_type(4))) float f32x4;

__device__ __forceinline__ u16 f2bf(float f) {
  union { float f; uint32_t u; } v; v.f = f;
  uint32_t u = v.u;
  uint32_t r = u + 0x7FFFu + ((u >> 16) & 1u);
  return (u16)(r >> 16);
}
__device__ __forceinline__ float bf2f(u16 h) {
  union { uint32_t u; float f; } v; v.u = ((uint32_t)h) << 16; return v.f;
}

__device__ __forceinline__ void async16(const void* g, void* l) {
  __builtin_amdgcn_global_load_lds(
      reinterpret_cast<const __attribute__((address_space(1))) uint32_t*>(
          reinterpret_cast<uintptr_t>(g)),
      reinterpret_cast<__attribute__((address_space(3))) uint32_t*>(
          reinterpret_cast<uintptr_t>(l)),
      16, 0, 0);
}

// ---- K0a: xbar = bf16(x - b_dec) ----
__global__ __launch_bounds__(256) void k_xbar(const float* __restrict__ x,
                                              const float* __restrict__ b_dec,
                                              u16* __restrict__ xbar) {
  int i = blockIdx.x * 256 + threadIdx.x;
  int base = i * 4;
  int col = base & (F_ - 1);
  float4 xv = *(const float4*)(x + base);
  float4 bv = *(const float4*)(b_dec + col);
  ushort4 o;
  o.x = f2bf(xv.x - bv.x); o.y = f2bf(xv.y - bv.y);
  o.z = f2bf(xv.z - bv.z); o.w = f2bf(xv.w - bv.w);
  *(ushort4*)(xbar + base) = o;
}

// ---- K0b: bf16 cast of W_enc ----
__global__ __launch_bounds__(256) void k_cast(const float* __restrict__ src,
                                              u16* __restrict__ dst) {
  size_t base = (size_t)(blockIdx.x * 256 + threadIdx.x) * 4;
  float4 v = *(const float4*)(src + base);
  ushort4 o; o.x = f2bf(v.x); o.y = f2bf(v.y); o.z = f2bf(v.z); o.w = f2bf(v.w);
  *(ushort4*)(dst + base) = o;
}

// ---- K0c: W_dec [F,H] fp32 -> W_decT [H,F] bf16 ----
__global__ __launch_bounds__(256) void k_transpose(const float* __restrict__ Wdec,
                                                   u16* __restrict__ WdecT) {
  __shared__ float tile[32][33];
  int hb = blockIdx.x * 32, fb = blockIdx.y * 32;
  int tx = threadIdx.x & 31, ty = threadIdx.x >> 5;  // ty 0..7
#pragma unroll
  for (int i = 0; i < 32; i += 8)
    tile[ty + i][tx] = Wdec[(size_t)(fb + ty + i) * H_ + hb + tx];
  __syncthreads();
#pragma unroll
  for (int i = 0; i < 32; i += 8)
    WdecT[(size_t)(hb + ty + i) * F_ + fb + tx] = f2bf(tile[tx][ty + i]);
}

// ---- K1: bf16 MFMA GEMM, XOR-swizzled LDS (conflict-free), bf16 output ----
__global__ __launch_bounds__(256) void k_gemm(const u16* __restrict__ A,
                                              const u16* __restrict__ Bm,
                                              const float* __restrict__ b_enc,
                                              u16* __restrict__ Cbf) {
  __shared__ u16 lA[128 * 32];
  __shared__ u16 lB[128 * 32];
  const int tid = threadIdx.x;
  const int lane = tid & 63, wave = tid >> 6;
  const int wm = wave >> 1, wn = wave & 1;
  const int bx = blockIdx.x, by = blockIdx.y;

  const int kcs = (tid & 3) ^ ((tid >> 3) & 3);  // swizzled source chunk
  const u16* gA0 = A + (size_t)(by * 128 + (tid >> 2)) * F_ + kcs * 8;
  const u16* gB0 = Bm + (size_t)(bx * 128 + (tid >> 2)) * F_ + kcs * 8;
  u16* lA0 = &lA[tid * 8];
  u16* lB0 = &lB[tid * 8];

  f32x4 acc[4][4] = {};
  const int lm = lane & 15;
  const int kcp = (((lane >> 4) ^ ((lm >> 1) & 3))) * 8;  // swizzled read offset

  for (int k0 = 0; k0 < F_; k0 += 32) {
    async16(gA0 + k0, lA0);
    async16(gA0 + 64 * F_ + k0, lA0 + 2048);
    async16(gB0 + k0, lB0);
    async16(gB0 + 64 * F_ + k0, lB0 + 2048);
    __syncthreads();
    bf16x8 av[4], bv[4];
#pragma unroll
    for (int i = 0; i < 4; ++i)
      av[i] = *(const bf16x8*)&lA[(wm * 64 + i * 16 + lm) * 32 + kcp];
#pragma unroll
    for (int j = 0; j < 4; ++j)
      bv[j] = *(const bf16x8*)&lB[(wn * 64 + j * 16 + lm) * 32 + kcp];
#pragma unroll
    for (int i = 0; i < 4; ++i)
#pragma unroll
      for (int j = 0; j < 4; ++j)
        acc[i][j] = __builtin_amdgcn_mfma_f32_16x16x32_bf16(av[i], bv[j], acc[i][j], 0, 0, 0);
    __syncthreads();
  }

#pragma unroll
  for (int i = 0; i < 4; ++i) {
    int rowg = by * 128 + wm * 64 + i * 16 + (lane >> 4) * 4;
#pragma unroll
    for (int j = 0; j < 4; ++j) {
      int colg = bx * 128 + wn * 64 + j * 16 + lm;
      float be = b_enc[colg];
      u16* cp = Cbf + (size_t)rowg * H_ + colg;
#pragma unroll
      for (int r = 0; r < 4; ++r)
        cp[(size_t)r * H_] = f2bf(acc[i][j][r] + be);
    }
  }
}

// ---- K2: per-row histogram select from bf16 a, LDS-staged single global pass ----
__global__ __launch_bounds__(256) void k_select(const u16* __restrict__ abf,
                                                int* __restrict__ candIdx,
                                                int* __restrict__ candCnt) {
  const int row = blockIdx.x, tid = threadIdx.x;
  const u16* arow = abf + (size_t)row * H_;
  __shared__ u16 sa[H_];        // 32 KB row stage
  __shared__ int hist[NBINS];   // 8 KB
  __shared__ int coarse[256];
  __shared__ float s_cut;
  __shared__ int s_cnt;
  for (int i = tid; i < NBINS; i += 256) hist[i] = 0;
  if (tid == 0) s_cnt = 0;
  __syncthreads();
  for (int i = tid; i < H_ / 8; i += 256) {
    u16x8 v = *(const u16x8*)(arow + i * 8);
    *(u16x8*)(sa + i * 8) = v;
#pragma unroll
    for (int c = 0; c < 8; ++c) {
      float fv = bf2f(v[c]);
      int b = (int)floorf((fv + 4.0f) * 256.0f);
      b = b < 0 ? 0 : (b > NBINS - 1 ? NBINS - 1 : b);
      atomicAdd(&hist[b], 1);
    }
  }
  __syncthreads();
  {
    int s = 0;
#pragma unroll
    for (int j = 0; j < 8; ++j) s += hist[tid * 8 + j];
    coarse[tid] = s;
  }
  __syncthreads();
  if (tid == 0) {
    int c = 0, ifound = 0;
    for (int t = 255; t >= 0; --t) {
      if (c + coarse[t] >= TOPK) {
        for (int b = t * 8 + 7; b >= t * 8; --b) {
          c += hist[b];
          if (c >= TOPK) { ifound = b; break; }
        }
        break;
      }
      c += coarse[t];
    }
    // margin: bf16-GEMM error (<=0.025 proven) + bf16 storage rounding (<=0.008)
    s_cut = ((float)ifound * (1.0f / 256.0f) - 4.0f) - 0.035f;
  }
  __syncthreads();
  const float cut = s_cut;
  for (int i = tid; i < H_ / 8; i += 256) {
    u16x8 v = *(const u16x8*)(sa + i * 8);
#pragma unroll
    for (int c = 0; c < 8; ++c) {
      if (bf2f(v[c]) >= cut) {
        int p = atomicAdd(&s_cnt, 1);
        if (p < MAXC) candIdx[row * MAXC + p] = i * 8 + c;
      }
    }
  }
  __syncthreads();
  if (tid == 0) candCnt[row] = s_cnt < MAXC ? s_cnt : MAXC;
}

// ---- K3: h-tiled fp64 refinement. Block = 16 rows x 512-wide h-tile:
// Wenc slice (2 MB) stays L2-resident, x slice (64 KB) LLC-hot.
// Per-lane summation order identical to previous round (bit-identical vals).
__global__ __launch_bounds__(256) void k_refine(const float* __restrict__ x,
                                               const float* __restrict__ b_dec,
                                               const float* __restrict__ Wenc,
                                               const float* __restrict__ b_enc,
                                               const int* __restrict__ candIdx,
                                               const int* __restrict__ candCnt,
                                               double* __restrict__ valsG) {
  const int g = blockIdx.x, t = blockIdx.y;   // x-major launch: tile t co-resident
  const int r0 = g * RG, h0 = t * TW;
  const int tid = threadIdx.x, lane = tid & 63, wave = tid >> 6;
  __shared__ int wl_rs[WLCAP];
  __shared__ int wl_h[WLCAP];
  __shared__ int wcnt;
  if (tid == 0) wcnt = 0;
  __syncthreads();
  for (int r = 0; r < RG; ++r) {
    const int cnt = candCnt[r0 + r];
    for (int s = tid; s < cnt; s += 256) {
      const int h = candIdx[(r0 + r) * MAXC + s];
      if ((unsigned)(h - h0) < TW) {
        int p = atomicAdd(&wcnt, 1);
        wl_rs[p] = (r << 8) | s;
        wl_h[p] = h;
      }
    }
  }
  __syncthreads();
  const int n = wcnt;

  float4 bd[4];
#pragma unroll
  for (int ch = 0; ch < 4; ++ch) bd[ch] = ((const float4*)b_dec)[ch * 64 + lane];

  // 2 candidates per wave iteration: 16 global loads in flight, 2 fp64 chains
  for (int e0 = wave * 2; e0 < n; e0 += 8) {
    const int e1 = (e0 + 1 < n) ? e0 + 1 : e0;
    const int rs0 = wl_rs[e0], hh0 = wl_h[e0];
    const int rs1 = wl_rs[e1], hh1 = wl_h[e1];
    const int ra = r0 + (rs0 >> 8), sl0 = rs0 & 255;
    const int rb = r0 + (rs1 >> 8), sl1 = rs1 & 255;
    const float4* xr0 = (const float4*)(x + (size_t)ra * F_);
    const float4* xr1 = (const float4*)(x + (size_t)rb * F_);
    const float4* wr0 = (const float4*)(Wenc + (size_t)hh0 * F_);
    const float4* wr1 = (const float4*)(Wenc + (size_t)hh1 * F_);
    float4 xv0[4], wv0[4], xv1[4], wv1[4];
#pragma unroll
    for (int ch = 0; ch < 4; ++ch) {
      xv0[ch] = xr0[ch * 64 + lane];
      wv0[ch] = wr0[ch * 64 + lane];
      xv1[ch] = xr1[ch * 64 + lane];
      wv1[ch] = wr1[ch * 64 + lane];
    }
    double s0 = 0.0, s1 = 0.0;
#pragma unroll
    for (int ch = 0; ch < 4; ++ch) {
      s0 += ((double)xv0[ch].x - (double)bd[ch].x) * (double)wv0[ch].x;
      s0 += ((double)xv0[ch].y - (double)bd[ch].y) * (double)wv0[ch].y;
      s0 += ((double)xv0[ch].z - (double)bd[ch].z) * (double)wv0[ch].z;
      s0 += ((double)xv0[ch].w - (double)bd[ch].w) * (double)wv0[ch].w;
      s1 += ((double)xv1[ch].x - (double)bd[ch].x) * (double)wv1[ch].x;
      s1 += ((double)xv1[ch].y - (double)bd[ch].y) * (double)wv1[ch].y;
      s1 += ((double)xv1[ch].z - (double)bd[ch].z) * (double)wv1[ch].z;
      s1 += ((double)xv1[ch].w - (double)bd[ch].w) * (double)wv1[ch].w;
    }
#pragma unroll
    for (int off = 32; off > 0; off >>= 1) {
      s0 += __shfl_xor(s0, off);
      s1 += __shfl_xor(s1, off);
    }
    if (lane == 0) {
      valsG[(size_t)ra * MAXC + sl0] = s0 + (double)b_enc[hh0];
      if (e1 != e0) valsG[(size_t)rb * MAXC + sl1] = s1 + (double)b_enc[hh1];
    }
  }
}

// ---- K3b: rank + scatter + zero-fill of f (pure write stream) ----
__global__ __launch_bounds__(256) void k_rank(const int* __restrict__ candIdx,
                                              const int* __restrict__ candCnt,
                                              const double* __restrict__ valsG,
                                              float* __restrict__ f,
                                              int* __restrict__ decIdx,
                                              float* __restrict__ decVal) {
  const int row = blockIdx.x, tid = threadIdx.x;
  __shared__ double vals[MAXC];
  __shared__ int idxs[MAXC];
  const int cnt = candCnt[row];
  for (int c = tid; c < cnt; c += 256) {
    vals[c] = valsG[(size_t)row * MAXC + c];
    idxs[c] = candIdx[row * MAXC + c];
  }
  float* frow = f + (size_t)row * H_;
  const f32x4 z4 = {0.f, 0.f, 0.f, 0.f};
  for (int i = tid; i < H_ / 4; i += 256)
    __builtin_nontemporal_store(z4, (f32x4*)frow + i);
  __syncthreads();
  for (int c = tid; c < cnt; c += 256) {
    const double v = vals[c];
    const int h = idxs[c];
    int rank = 0;
    for (int o = 0; o < cnt; ++o) {
      double vo = vals[o];
      rank += (vo > v) || (vo == v && idxs[o] < h);  // jax tie-break: lower idx first
    }
    if (rank < TOPK) {
      float fv = v > 0.0 ? (float)v : 0.0f;
      frow[h] = fv;
      decIdx[row * TOPK + rank] = h;
      decVal[row * TOPK + rank] = fv;
    }
  }
}

// ---- K4: sparse decode: xhat[b,:] = sum_j val_j * W_decT[idx_j,:] + b_dec ----
__global__ __launch_bounds__(256) void k_decode(const int* __restrict__ decIdx,
                                               const float* __restrict__ decVal,
                                               const u16* __restrict__ WdecT,
                                               const float* __restrict__ b_dec,
                                               float* __restrict__ xhat) {
  const int row = blockIdx.x, tid = threadIdx.x;
  __shared__ int sIdx[TOPK];
  __shared__ float sVal[TOPK];
  if (tid < TOPK) {
    sIdx[tid] = decIdx[row * TOPK + tid];
    sVal[tid] = decVal[row * TOPK + tid];
  }
  __syncthreads();
  const int fb = tid * 4;
  float4 bd = *(const float4*)(b_dec + fb);
  float a0 = bd.x, a1 = bd.y, a2 = bd.z, a3 = bd.w;
#pragma unroll 8
  for (int j = 0; j < TOPK; ++j) {
    const float v = sVal[j];
    const ushort4 w = *(const ushort4*)(WdecT + (size_t)sIdx[j] * F_ + fb);
    a0 += v * bf2f(w.x); a1 += v * bf2f(w.y);
    a2 += v * bf2f(w.z); a3 += v * bf2f(w.w);
  }
  float4 o; o.x = a0; o.y = a1; o.z = a2; o.w = a3;
  *(float4*)(xhat + (size_t)row * F_ + fb) = o;
}

extern "C" void kernel_launch(void* const* d_in, const int* in_sizes, int n_in,
                              void* d_out, int out_size, void* d_ws, size_t ws_size,
                              hipStream_t stream) {
  const float* x    = (const float*)d_in[0];
  const float* Wenc = (const float*)d_in[1];
  const float* benc = (const float*)d_in[2];
  const float* Wdec = (const float*)d_in[3];
  const float* bdec = (const float*)d_in[4];

  float* out  = (float*)d_out;
  float* f    = out;                       // [4096][16384] fp32
  float* xhat = out + (size_t)B_ * H_;     // [4096][1024]
  // bf16 'a' lives in the upper half of the f region (fully consumed by
  // k_select before k_rank zero-fills f) — no ws growth.
  u16* abf = (u16*)(f + (size_t)B_ * H_ / 2);  // 128 MB

  char* ws = (char*)d_ws;
  u16*  xbar    = (u16*)ws;                             // 8 MB (dead after gemm)
  double* valsG = (double*)ws;                          // 6 MB, reuses xbar slot
  u16*  wencb   = (u16*)(ws + (size_t)(8)  * 1048576);  // 32 MB
  u16*  wdecT   = (u16*)(ws + (size_t)(40) * 1048576);  // 32 MB
  int*  candIdx = (int*)(ws + (size_t)(72) * 1048576);  // 3 MB
  int*  candCnt = (int*)(ws + (size_t)(75) * 1048576);  // 16 KB
  int*  decIdx  = (int*)(ws + (size_t)(76) * 1048576);  // 1 MB
  float* decVal = (float*)(ws + (size_t)(77) * 1048576);// 1 MB

  k_xbar<<<B_ * F_ / 1024, 256, 0, stream>>>(x, bdec, xbar);
  k_cast<<<H_ * F_ / 1024, 256, 0, stream>>>(Wenc, wencb);
  k_transpose<<<dim3(H_ / 32, F_ / 32), 256, 0, stream>>>(Wdec, wdecT);
  k_gemm<<<dim3(H_ / 128, B_ / 128), 256, 0, stream>>>(xbar, wencb, benc, abf);
  k_select<<<B_, 256, 0, stream>>>(abf, candIdx, candCnt);
  k_refine<<<dim3(B_ / RG, H_ / TW), 256, 0, stream>>>(x, bdec, Wenc, benc,
                                                       candIdx, candCnt, valsG);
  k_rank<<<B_, 256, 0, stream>>>(candIdx, candCnt, valsG, f, decIdx, decVal);
  k_decode<<<B_, 256, 0, stream>>>(decIdx, decVal, wdecT, bdec, xhat);
}